// Round 11
// baseline (461.187 us; speedup 1.0000x reference)
//
#include <hip/hip_runtime.h>
#include <hip/hip_fp16.h>

#define NN 100000
#define NE 3200000
#define SCAN_CHUNK 1024

// bucket sort params
#define BSH 8
#define BKT_NODES 256                       // 1 << BSH
#define NBKT ((NN + BKT_NODES - 1) / BKT_NODES)   // 391
#define BIN_BLOCKS 256
#define EPB ((NE + BIN_BLOCKS - 1) / BIN_BLOCKS)  // 12500
#define GH (NBKT * BIN_BLOCKS)                    // 100096

typedef unsigned int uint;
typedef unsigned short ushort;
typedef __attribute__((ext_vector_type(8))) _Float16 half8;
typedef __attribute__((ext_vector_type(4))) float f32x4;

// async global->LDS, 16B per lane; dest = wave-uniform base + lane*16
__device__ inline void gload16(const void* g, void* l) {
    __builtin_amdgcn_global_load_lds(
        (const __attribute__((address_space(1))) void*)g,
        (__attribute__((address_space(3))) void*)l, 16, 0, 0);
}

// fp16 helpers (RNE via v_cvt_f16_f32)
__device__ inline uint f2h_pair(float a, float b) {
    return (uint)__half_as_ushort(__float2half(a)) |
           ((uint)__half_as_ushort(__float2half(b)) << 16);
}
__device__ inline float h2f_lo(uint u) { return __half2float(__ushort_as_half((ushort)(u & 0xFFFFu))); }
__device__ inline float h2f_hi(uint u) { return __half2float(__ushort_as_half((ushort)(u >> 16))); }
// split fp32 -> fp16 hi + lo (x ~= hi + lo)
__device__ inline void splitH(float x, ushort& h, ushort& l) {
    __half hh = __float2half(x);
    h = __half_as_ushort(hh);
    l = __half_as_ushort(__float2half(x - __half2float(hh)));
}

// ---------------- bucket histogram ----------------
__global__ __launch_bounds__(256) void hist_bkt(const int* __restrict__ dst,
                                                int* __restrict__ ghist) {
    __shared__ int h[NBKT];
    int t = threadIdx.x;
    for (int i = t; i < NBKT; i += 256) h[i] = 0;
    __syncthreads();
    int beg = blockIdx.x * EPB;
    int end = beg + EPB; if (end > NE) end = NE;
    for (int e = beg + t; e < end; e += 256)
        atomicAdd(&h[dst[e] >> BSH], 1);
    __syncthreads();
    for (int i = t; i < NBKT; i += 256)
        ghist[i * BIN_BLOCKS + blockIdx.x] = h[i];
}

// ---------------- hierarchical scan: phase 1 ----------------
__global__ __launch_bounds__(256) void scan_p1(const int* __restrict__ cnt,
                                               int* __restrict__ bsum, int N) {
    int t = threadIdx.x;
    int base = blockIdx.x * SCAN_CHUNK + t * 4;
    int s = 0;
#pragma unroll
    for (int q = 0; q < 4; q++) {
        int i = base + q;
        if (i < N) s += cnt[i];
    }
    __shared__ int red[4];
#pragma unroll
    for (int off = 32; off; off >>= 1) s += __shfl_down(s, off, 64);
    if ((t & 63) == 0) red[t >> 6] = s;
    __syncthreads();
    if (t == 0) bsum[blockIdx.x] = red[0] + red[1] + red[2] + red[3];
}

// ---------------- phase 2 ----------------
__global__ void scan_p2(int* __restrict__ bsum, int nb) {
    __shared__ int s[128];
    int t = threadIdx.x;
    int v = (t < nb) ? bsum[t] : 0;
    s[t] = v;
    __syncthreads();
    for (int off = 1; off < 128; off <<= 1) {
        int x = s[t];
        int add = (t >= off) ? s[t - off] : 0;
        __syncthreads();
        s[t] = x + add;
        __syncthreads();
    }
    if (t < nb) bsum[t] = s[t] - v;  // exclusive
}

// ---------------- phase 3: in-place exclusive scan ----------------
__global__ __launch_bounds__(256) void scan_p3_plain(int* __restrict__ data,
                                                     const int* __restrict__ bsum, int N) {
    __shared__ int ts[256];
    int t = threadIdx.x;
    int base = blockIdx.x * SCAN_CHUNK + t * 4;
    int c[4];
    int s = 0;
#pragma unroll
    for (int q = 0; q < 4; q++) {
        int i = base + q;
        c[q] = (i < N) ? data[i] : 0;
        s += c[q];
    }
    ts[t] = s;
    __syncthreads();
    for (int off = 1; off < 256; off <<= 1) {
        int x = ts[t];
        int add = (t >= off) ? ts[t - off] : 0;
        __syncthreads();
        ts[t] = x + add;
        __syncthreads();
    }
    int run = bsum[blockIdx.x] + ts[t] - s;
#pragma unroll
    for (int q = 0; q < 4; q++) {
        int i = base + q;
        if (i < N) { data[i] = run; run += c[q]; }
    }
}

// ---------------- bin edges into bucket-segmented records ----------------
__global__ __launch_bounds__(256) void bin_edges(const int* __restrict__ src,
                                                 const int* __restrict__ dst,
                                                 const int* __restrict__ ghist,
                                                 uint* __restrict__ binned) {
    __shared__ int cur[NBKT];
    int t = threadIdx.x;
    for (int i = t; i < NBKT; i += 256) cur[i] = ghist[i * BIN_BLOCKS + blockIdx.x];
    __syncthreads();
    int beg = blockIdx.x * EPB;
    int end = beg + EPB; if (end > NE) end = NE;
    for (int e = beg + t; e < end; e += 256) {
        int d = dst[e];
        int b = d >> BSH;
        int p = atomicAdd(&cur[b], 1);
        binned[p] = ((uint)src[e] << BSH) | (uint)(d & (BKT_NODES - 1));
    }
}

// ---------------- fused: per-bucket degree count + local scan -> rowptr + dinv ----------------
// rowptr[node] = bucketBeg + exclusive-prefix-within-bucket (buckets contiguous in edge space).
__global__ __launch_bounds__(256) void bucket_rowptr(const uint* __restrict__ binned,
                                                     const int* __restrict__ ghist,
                                                     int* __restrict__ rowptr,
                                                     float* __restrict__ dinv) {
    __shared__ int c[BKT_NODES];
    __shared__ int ts[256];
    int t = threadIdx.x;
    int bkt = blockIdx.x;
    c[t] = 0;
    __syncthreads();
    int beg = ghist[bkt * BIN_BLOCKS];
    int end = (bkt == NBKT - 1) ? NE : ghist[(bkt + 1) * BIN_BLOCKS];
    for (int j = beg + t; j < end; j += 256)
        atomicAdd(&c[binned[j] & (BKT_NODES - 1)], 1);
    __syncthreads();
    int ci = c[t];
    ts[t] = ci;
    __syncthreads();
    for (int off = 1; off < 256; off <<= 1) {
        int x = ts[t];
        int add = (t >= off) ? ts[t - off] : 0;
        __syncthreads();
        ts[t] = x + add;
        __syncthreads();
    }
    int node = bkt * BKT_NODES + t;
    if (node < NN) {
        rowptr[node] = beg + ts[t] - ci;  // exclusive prefix
        dinv[node] = 1.0f / sqrtf((float)(ci + 1));  // +1 self-loop
    }
    if (bkt == 0 && t == 0) rowptr[NN] = NE;
}

// ---------------- per-bucket CSR fill ----------------
__global__ __launch_bounds__(256) void csr_fill(const uint* __restrict__ binned,
                                                const int* __restrict__ ghist,
                                                const int* __restrict__ rowptr,
                                                int* __restrict__ col) {
    __shared__ int fill[BKT_NODES];
    int t = threadIdx.x;
    int bkt = blockIdx.x;
    for (int i = t; i < BKT_NODES; i += 256) fill[i] = 0;
    __syncthreads();
    int beg = ghist[bkt * BIN_BLOCKS];
    int end = (bkt == NBKT - 1) ? NE : ghist[(bkt + 1) * BIN_BLOCKS];
    int base = bkt * BKT_NODES;
    for (int j = beg + t; j < end; j += 256) {
        uint r = binned[j];
        int dl = r & (BKT_NODES - 1);
        int p = rowptr[base + dl] + atomicAdd(&fill[dl], 1);
        col[p] = (int)(r >> BSH);
    }
}

// ---------------- W transpose + fp16 hi/lo split: W[K][128] -> Wt[128][K] ----------------
template <int K>
__global__ __launch_bounds__(256) void wsplit(const float* __restrict__ W,
                                              ushort* __restrict__ Wth,
                                              ushort* __restrict__ Wtl) {
    __shared__ float tile[32][128];
    int t = threadIdx.x;
    int kb = blockIdx.x;
    {
        int k = t >> 3, cq = t & 7;
#pragma unroll
        for (int q = 0; q < 4; q++) {
            float4 v = *(const float4*)&W[(size_t)(kb * 32 + k) * 128 + cq * 16 + q * 4];
            *(float4*)&tile[k][cq * 16 + q * 4] = v;
        }
    }
    __syncthreads();
    {
        int c = t >> 1, g = t & 1;
        ushort hs[16], ls[16];
#pragma unroll
        for (int i = 0; i < 16; i++) splitH(tile[g * 16 + i][c], hs[i], ls[i]);
        uint h[8], lo[8];
#pragma unroll
        for (int i = 0; i < 8; i++) {
            h[i] = (uint)hs[2 * i] | ((uint)hs[2 * i + 1] << 16);
            lo[i] = (uint)ls[2 * i] | ((uint)ls[2 * i + 1] << 16);
        }
        size_t o = (size_t)c * K + kb * 32 + g * 16;
        *(uint4*)&Wth[o] = make_uint4(h[0], h[1], h[2], h[3]);
        *(uint4*)&Wth[o + 8] = make_uint4(h[4], h[5], h[6], h[7]);
        *(uint4*)&Wtl[o] = make_uint4(lo[0], lo[1], lo[2], lo[3]);
        *(uint4*)&Wtl[o + 8] = make_uint4(lo[4], lo[5], lo[6], lo[7]);
    }
}

// ---------------- MFMA GEMM (fp32 input): A staged RAW fp32 via global_load_lds ----------------
// A LDS: 8 kq-planes (kq = 4-fp32 quad) x 128 rows x 16B = 16 KB. cvt fp32->fp16 AFTER the
// LDS fragment read (VALU is idle anyway); staging is pure async DMA -> no serialized reg chain.
template <int K>
__global__ __launch_bounds__(256) void mfma_gemm_f32(const float* __restrict__ X,
                                                     const ushort* __restrict__ Wth,
                                                     const ushort* __restrict__ Wtl,
                                                     const float* __restrict__ dinv,
                                                     uint* __restrict__ Y, int M) {
    __shared__ char smem[32 * 1024];
    char* aF = smem;              // 16 KB fp32 A
    char* bH = smem + 16384;      // 8 KB
    char* bL = smem + 24576;      // 8 KB
    int tid = threadIdx.x;
    int w = tid >> 6, l = tid & 63;
    int rowBase = blockIdx.x * 128;

    f32x4 acc[2][8];
#pragma unroll
    for (int mf = 0; mf < 2; mf++)
#pragma unroll
        for (int n = 0; n < 8; n++) acc[mf][n] = (f32x4){0.f, 0.f, 0.f, 0.f};

    int fc = l & 15, fkg = l >> 4;

    for (int kt = 0; kt < K; kt += 32) {
        // ---- A async global->LDS: chunk c -> (kq = c>>7, row = c&127), src per-lane ----
#pragma unroll
        for (int i = 0; i < 4; i++) {
            int cb = (i * 4 + w) * 64;   // wave-uniform chunk base
            int c = cb + l;
            int kq = c >> 7, row = c & 127;
            int gr = rowBase + row;
            if (gr >= M) gr = 0;  // clamp; epilogue masks these rows
            gload16(&X[(size_t)gr * K + kt + kq * 4], aF + cb * 16);
        }
        // ---- B async global->LDS (kg-plane chunk order) ----
#pragma unroll
        for (int i = 0; i < 2; i++) {
            int cb = (i * 4 + w) * 64;
            int c = cb + l;
            int kg = c >> 7, colb = c & 127;
            size_t go = (size_t)colb * K + kt + kg * 8;
            gload16(&Wth[go], bH + cb * 16);
            gload16(&Wtl[go], bL + cb * 16);
        }
        __syncthreads();

#pragma unroll
        for (int mf = 0; mf < 2; mf++) {
            int mrow = (2 * w + mf) * 16 + fc;
            f32x4 p0 = *(const f32x4*)(aF + (2 * fkg) * 2048 + mrow * 16);
            f32x4 p1 = *(const f32x4*)(aF + (2 * fkg + 1) * 2048 + mrow * 16);
            half8 av;
            av[0] = (_Float16)p0[0]; av[1] = (_Float16)p0[1];
            av[2] = (_Float16)p0[2]; av[3] = (_Float16)p0[3];
            av[4] = (_Float16)p1[0]; av[5] = (_Float16)p1[1];
            av[6] = (_Float16)p1[2]; av[7] = (_Float16)p1[3];
#pragma unroll
            for (int n = 0; n < 8; n++) {
                int boff = fkg * 2048 + (16 * n + fc) * 16;
                half8 bh = *(const half8*)(bH + boff);
                half8 bl = *(const half8*)(bL + boff);
                acc[mf][n] = __builtin_amdgcn_mfma_f32_16x16x32_f16(av, bh, acc[mf][n], 0, 0, 0);
                acc[mf][n] = __builtin_amdgcn_mfma_f32_16x16x32_f16(av, bl, acc[mf][n], 0, 0, 0);
            }
        }
        __syncthreads();
    }

    // ---- epilogue: scale by dinv, pack fp16 pairs ----
#pragma unroll
    for (int mf = 0; mf < 2; mf++) {
        float dscale[4];
#pragma unroll
        for (int r = 0; r < 4; r++) {
            int row = rowBase + (2 * w + mf) * 16 + fkg * 4 + r;
            dscale[r] = (row < M) ? dinv[row] : 0.f;
        }
#pragma unroll
        for (int n = 0; n < 8; n++) {
#pragma unroll
            for (int r = 0; r < 4; r++) {
                float val = acc[mf][n][r] * dscale[r];
                float p = __shfl_xor(val, 1, 64);
                int row = rowBase + (2 * w + mf) * 16 + fkg * 4 + r;
                if (!(l & 1) && row < M)
                    Y[(size_t)row * 64 + 8 * n + (fc >> 1)] = f2h_pair(val, p);
            }
        }
    }
}

// ---------------- MFMA GEMM (fp16 input, K=128): all staging via global_load_lds ----------------
__global__ __launch_bounds__(256) void mfma_gemm_f16(const ushort* __restrict__ Xh,
                                                     const ushort* __restrict__ Wth,
                                                     const ushort* __restrict__ Wtl,
                                                     const float* __restrict__ dinv,
                                                     uint* __restrict__ Y, int M) {
    __shared__ char smem[24 * 1024];
    char* aP = smem;
    char* bH = smem + 8192;
    char* bL = smem + 16384;
    int tid = threadIdx.x;
    int w = tid >> 6, l = tid & 63;
    int rowBase = blockIdx.x * 128;

    f32x4 acc[2][8];
#pragma unroll
    for (int mf = 0; mf < 2; mf++)
#pragma unroll
        for (int n = 0; n < 8; n++) acc[mf][n] = (f32x4){0.f, 0.f, 0.f, 0.f};

    int fc = l & 15, fkg = l >> 4;
    int aoff0 = fkg * 2048 + ((2 * w + 0) * 16 + fc) * 16;
    int aoff1 = fkg * 2048 + ((2 * w + 1) * 16 + fc) * 16;

    for (int kt = 0; kt < 128; kt += 32) {
#pragma unroll
        for (int i = 0; i < 2; i++) {
            int cb = (i * 4 + w) * 64;   // wave-uniform
            int c = cb + l;
            int kg = c >> 7, idx = c & 127;
            gload16(&Xh[(size_t)(rowBase + idx) * 128 + kt + kg * 8], aP + cb * 16);
            gload16(&Wth[(size_t)idx * 128 + kt + kg * 8], bH + cb * 16);
            gload16(&Wtl[(size_t)idx * 128 + kt + kg * 8], bL + cb * 16);
        }
        __syncthreads();
        half8 av0 = *(const half8*)(aP + aoff0);
        half8 av1 = *(const half8*)(aP + aoff1);
#pragma unroll
        for (int n = 0; n < 8; n++) {
            int boff = fkg * 2048 + (16 * n + fc) * 16;
            half8 bh = *(const half8*)(bH + boff);
            half8 bl = *(const half8*)(bL + boff);
            acc[0][n] = __builtin_amdgcn_mfma_f32_16x16x32_f16(av0, bh, acc[0][n], 0, 0, 0);
            acc[0][n] = __builtin_amdgcn_mfma_f32_16x16x32_f16(av0, bl, acc[0][n], 0, 0, 0);
            acc[1][n] = __builtin_amdgcn_mfma_f32_16x16x32_f16(av1, bh, acc[1][n], 0, 0, 0);
            acc[1][n] = __builtin_amdgcn_mfma_f32_16x16x32_f16(av1, bl, acc[1][n], 0, 0, 0);
        }
        __syncthreads();
    }

#pragma unroll
    for (int mf = 0; mf < 2; mf++) {
        float dscale[4];
#pragma unroll
        for (int r = 0; r < 4; r++) {
            int row = rowBase + (2 * w + mf) * 16 + fkg * 4 + r;
            dscale[r] = (row < M) ? dinv[row] : 0.f;
        }
#pragma unroll
        for (int n = 0; n < 8; n++) {
#pragma unroll
            for (int r = 0; r < 4; r++) {
                float val = acc[mf][n][r] * dscale[r];
                float p = __shfl_xor(val, 1, 64);
                int row = rowBase + (2 * w + mf) * 16 + fkg * 4 + r;
                if (!(l & 1) && row < M)
                    Y[(size_t)row * 64 + 8 * n + (fc >> 1)] = f2h_pair(val, p);
            }
        }
    }
}

// ---------------- small GEMM N=5 K=128 fp16 in, fused dinv-scale + fp16 pack out ----------------
__global__ __launch_bounds__(256) void gemm_n5h(const uint4* __restrict__ Xh,
                                                const float* __restrict__ W,
                                                const float* __restrict__ dinv,
                                                uint4* __restrict__ hc, int M) {
    __shared__ float wl[640];
    int t = threadIdx.x;
    for (int i = t; i < 640; i += 256) wl[i] = W[i];
    __syncthreads();
    int row = blockIdx.x * 256 + t;
    if (row >= M) return;
    float acc0 = 0.f, acc1 = 0.f, acc2 = 0.f, acc3 = 0.f, acc4 = 0.f;
#pragma unroll
    for (int kq = 0; kq < 16; kq++) {
        uint4 v = Xh[(size_t)row * 16 + kq];
        uint uu[4] = {v.x, v.y, v.z, v.w};
#pragma unroll
        for (int e = 0; e < 4; e++) {
            float x0 = h2f_lo(uu[e]);
            float x1 = h2f_hi(uu[e]);
            int k = kq * 8 + e * 2;
            acc0 = fmaf(x0, wl[k * 5 + 0], acc0); acc0 = fmaf(x1, wl[k * 5 + 5], acc0);
            acc1 = fmaf(x0, wl[k * 5 + 1], acc1); acc1 = fmaf(x1, wl[k * 5 + 6], acc1);
            acc2 = fmaf(x0, wl[k * 5 + 2], acc2); acc2 = fmaf(x1, wl[k * 5 + 7], acc2);
            acc3 = fmaf(x0, wl[k * 5 + 3], acc3); acc3 = fmaf(x1, wl[k * 5 + 8], acc3);
            acc4 = fmaf(x0, wl[k * 5 + 4], acc4); acc4 = fmaf(x1, wl[k * 5 + 9], acc4);
        }
    }
    float di = dinv[row];
    hc[row] = make_uint4(f2h_pair(acc0 * di, acc1 * di),
                         f2h_pair(acc2 * di, acc3 * di),
                         f2h_pair(acc4 * di, 0.f), 0u);
}

#define ACC8H(v)                              \
    a0 += h2f_lo(v.x); a1 += h2f_hi(v.x);     \
    a2 += h2f_lo(v.y); a3 += h2f_hi(v.y);     \
    a4 += h2f_lo(v.z); a5 += h2f_hi(v.z);     \
    a6 += h2f_lo(v.w); a7 += h2f_hi(v.w);

// ---------------- CSR aggregation, dim 128 (fp16): wave/node, out = fp16 rows ----------------
__global__ __launch_bounds__(256) void agg128_v3(const uint4* __restrict__ hb4,
                                                 const int* __restrict__ rowptr,
                                                 const int* __restrict__ col,
                                                 const float* __restrict__ dinv,
                                                 const float* __restrict__ bias,
                                                 uint4* __restrict__ out, int N, int do_relu) {
    int wave = threadIdx.x >> 6;
    int lane = threadIdx.x & 63;
    int node = blockIdx.x * 4 + wave;
    if (node >= N) return;
    int g = lane >> 4;    // edge slot 0..3
    int q = lane & 15;    // dim-octet: dims [q*8, q*8+8)
    int beg = rowptr[node], end = rowptr[node + 1];
    float a0 = 0.f, a1 = 0.f, a2 = 0.f, a3 = 0.f, a4 = 0.f, a5 = 0.f, a6 = 0.f, a7 = 0.f;

    int j = beg;
    for (; j + 16 <= end; j += 16) {
        int s0 = col[j + g];
        int s1 = col[j + 4 + g];
        int s2 = col[j + 8 + g];
        int s3 = col[j + 12 + g];
        uint4 v0 = hb4[(size_t)s0 * 16 + q];
        uint4 v1 = hb4[(size_t)s1 * 16 + q];
        uint4 v2 = hb4[(size_t)s2 * 16 + q];
        uint4 v3 = hb4[(size_t)s3 * 16 + q];
        ACC8H(v0); ACC8H(v1); ACC8H(v2); ACC8H(v3);
    }
    if (j + 8 <= end) {
        int s0 = col[j + g];
        int s1 = col[j + 4 + g];
        uint4 v0 = hb4[(size_t)s0 * 16 + q];
        uint4 v1 = hb4[(size_t)s1 * 16 + q];
        ACC8H(v0); ACC8H(v1);
        j += 8;
    }
    if (j < end) {
        int jj0 = j + g, jj1 = j + 4 + g;
        bool p0 = jj0 < end, p1 = jj1 < end;
        int s0 = p0 ? col[jj0] : node;
        int s1 = p1 ? col[jj1] : node;
        uint4 v0 = hb4[(size_t)s0 * 16 + q];
        uint4 v1 = hb4[(size_t)s1 * 16 + q];
        if (!p0) v0 = make_uint4(0u, 0u, 0u, 0u);
        if (!p1) v1 = make_uint4(0u, 0u, 0u, 0u);
        ACC8H(v0); ACC8H(v1);
    }
#pragma unroll
    for (int off = 16; off <= 32; off <<= 1) {
        a0 += __shfl_xor(a0, off, 64);
        a1 += __shfl_xor(a1, off, 64);
        a2 += __shfl_xor(a2, off, 64);
        a3 += __shfl_xor(a3, off, 64);
        a4 += __shfl_xor(a4, off, 64);
        a5 += __shfl_xor(a5, off, 64);
        a6 += __shfl_xor(a6, off, 64);
        a7 += __shfl_xor(a7, off, 64);
    }
    if (g == 0) {
        uint4 vs = hb4[(size_t)node * 16 + q];  // self term (pre-scaled)
        ACC8H(vs);
        float di = dinv[node];
        const float4* bias4 = (const float4*)bias;
        float4 bb0 = bias4[q * 2], bb1 = bias4[q * 2 + 1];
        float o0 = a0 * di + bb0.x, o1 = a1 * di + bb0.y;
        float o2 = a2 * di + bb0.z, o3 = a3 * di + bb0.w;
        float o4 = a4 * di + bb1.x, o5 = a5 * di + bb1.y;
        float o6 = a6 * di + bb1.z, o7 = a7 * di + bb1.w;
        if (do_relu) {
            o0 = fmaxf(o0, 0.f); o1 = fmaxf(o1, 0.f);
            o2 = fmaxf(o2, 0.f); o3 = fmaxf(o3, 0.f);
            o4 = fmaxf(o4, 0.f); o5 = fmaxf(o5, 0.f);
            o6 = fmaxf(o6, 0.f); o7 = fmaxf(o7, 0.f);
        }
        out[(size_t)node * 16 + q] =
            make_uint4(f2h_pair(o0, o1), f2h_pair(o2, o3), f2h_pair(o4, o5), f2h_pair(o6, o7));
    }
}

// ---------------- CSR aggregation, dim 5 (fp16 packed rows): thread per node ----------------
__global__ void agg5_v2(const uint4* __restrict__ hc, const int* __restrict__ rowptr,
                        const int* __restrict__ col, const float* __restrict__ dinv,
                        const float* __restrict__ b3, float* __restrict__ out, int N) {
    int node = blockIdx.x * 256 + threadIdx.x;
    if (node >= N) return;
    float a0 = 0.f, a1 = 0.f, a2 = 0.f, a3 = 0.f, a4 = 0.f;
    int beg = rowptr[node], end = rowptr[node + 1];
#pragma unroll 2
    for (int j = beg; j < end; ++j) {
        uint4 v = hc[col[j]];
        a0 += h2f_lo(v.x); a1 += h2f_hi(v.x);
        a2 += h2f_lo(v.y); a3 += h2f_hi(v.y);
        a4 += h2f_lo(v.z);
    }
    uint4 vs = hc[node];
    a0 += h2f_lo(vs.x); a1 += h2f_hi(vs.x);
    a2 += h2f_lo(vs.y); a3 += h2f_hi(vs.y);
    a4 += h2f_lo(vs.z);
    float di = dinv[node];
    out[node * 5 + 0] = a0 * di + b3[0];
    out[node * 5 + 1] = a1 * di + b3[1];
    out[node * 5 + 2] = a2 * di + b3[2];
    out[node * 5 + 3] = a3 * di + b3[3];
    out[node * 5 + 4] = a4 * di + b3[4];
}

static inline size_t align512(size_t x) { return (x + 511) & ~(size_t)511; }

extern "C" void kernel_launch(void* const* d_in, const int* in_sizes, int n_in,
                              void* d_out, int out_size, void* d_ws, size_t ws_size,
                              hipStream_t stream) {
    const float* x  = (const float*)d_in[0];
    const int* ei   = (const int*)d_in[1];
    const float* W1 = (const float*)d_in[2];
    const float* b1 = (const float*)d_in[3];
    const float* W2 = (const float*)d_in[4];
    const float* b2 = (const float*)d_in[5];
    const float* W3 = (const float*)d_in[6];
    const float* b3 = (const float*)d_in[7];
    const int* src = ei;
    const int* dst = ei + NE;

    char* ws = (char*)d_ws;
    size_t off = 0;
    int* rowptr = (int*)(ws + off);     off += align512((size_t)(NN + 1) * 4);
    float* dinv = (float*)(ws + off);   off += align512((size_t)NN * 4);
    int* bsum = (int*)(ws + off);       off += align512((size_t)128 * 4);
    int* ghist = (int*)(ws + off);      off += align512((size_t)GH * 4);
    ushort* wt1h = (ushort*)(ws + off); off += align512((size_t)128 * 384 * 2);
    ushort* wt1l = (ushort*)(ws + off); off += align512((size_t)128 * 384 * 2);
    ushort* wt2h = (ushort*)(ws + off); off += align512((size_t)128 * 128 * 2);
    ushort* wt2l = (ushort*)(ws + off); off += align512((size_t)128 * 128 * 2);
    int* col = (int*)(ws + off);        off += align512((size_t)NE * 4);
    uint* hb = (uint*)(ws + off);       off += align512((size_t)NN * 64 * 4);   // fp16 dinv*h (packed)
    char* bufF = (char*)(ws + off);     off += align512((size_t)NN * 128 * 4);  // fp16 agg out (oversized: OOB-tile reads stay in ws)
    uint4* hc = (uint4*)(ws + off);     off += align512((size_t)NN * 16);       // packed fp16 dinv*h5
    uint* binned = (uint*)bufF;  // alias: binned dead before bufF's first write
    (void)ws_size;

    // ---- W transpose + fp16 hi/lo split ----
    wsplit<384><<<12, 256, 0, stream>>>(W1, wt1h, wt1l);
    wsplit<128><<<4, 256, 0, stream>>>(W2, wt2h, wt2l);

    // ---- build CSR (by dst) + dinv, bucket-sorted for write locality ----
    hist_bkt<<<BIN_BLOCKS, 256, 0, stream>>>(dst, ghist);
    {
        int nb = (GH + SCAN_CHUNK - 1) / SCAN_CHUNK;  // 98
        scan_p1<<<nb, 256, 0, stream>>>(ghist, bsum, GH);
        scan_p2<<<1, 128, 0, stream>>>(bsum, nb);
        scan_p3_plain<<<nb, 256, 0, stream>>>(ghist, bsum, GH);
    }
    bin_edges<<<BIN_BLOCKS, 256, 0, stream>>>(src, dst, ghist, binned);
    bucket_rowptr<<<NBKT, 256, 0, stream>>>(binned, ghist, rowptr, dinv);
    csr_fill<<<NBKT, 256, 0, stream>>>(binned, ghist, rowptr, col);

    int gemm_blocks = (NN + 127) / 128;  // 782
    // ---- layer 1 ----
    mfma_gemm_f32<384><<<gemm_blocks, 256, 0, stream>>>(x, wt1h, wt1l, dinv, hb, NN);
    agg128_v3<<<(NN + 3) / 4, 256, 0, stream>>>((const uint4*)hb, rowptr, col, dinv, b1,
                                                (uint4*)bufF, NN, 1);
    // ---- layer 2 ----
    mfma_gemm_f16<<<gemm_blocks, 256, 0, stream>>>((const ushort*)bufF, wt2h, wt2l, dinv, hb, NN);
    agg128_v3<<<(NN + 3) / 4, 256, 0, stream>>>((const uint4*)hb, rowptr, col, dinv, b2,
                                                (uint4*)bufF, NN, 1);
    // ---- layer 3 ----
    gemm_n5h<<<(NN + 255) / 256, 256, 0, stream>>>((const uint4*)bufF, W3, dinv, hc, NN);
    agg5_v2<<<(NN + 255) / 256, 256, 0, stream>>>(hc, rowptr, col, dinv, b3, (float*)d_out, NN);
}

// Round 12
// 442.071 us; speedup vs baseline: 1.0432x; 1.0432x over previous
//
#include <hip/hip_runtime.h>
#include <hip/hip_fp16.h>

#define NN 100000
#define NE 3200000
#define SCAN_CHUNK 1024

// bucket sort params
#define BSH 8
#define BKT_NODES 256                       // 1 << BSH
#define NBKT ((NN + BKT_NODES - 1) / BKT_NODES)   // 391
#define BIN_BLOCKS 256
#define EPB ((NE + BIN_BLOCKS - 1) / BIN_BLOCKS)  // 12500
#define GH (NBKT * BIN_BLOCKS)                    // 100096

typedef unsigned int uint;
typedef unsigned short ushort;
typedef __attribute__((ext_vector_type(8))) _Float16 half8;
typedef __attribute__((ext_vector_type(4))) float f32x4;

// async global->LDS, 16B per lane; dest = wave-uniform base + lane*16
__device__ inline void gload16(const void* g, void* l) {
    __builtin_amdgcn_global_load_lds(
        (const __attribute__((address_space(1))) void*)g,
        (__attribute__((address_space(3))) void*)l, 16, 0, 0);
}

// fp16 helpers (RNE via v_cvt_f16_f32)
__device__ inline uint f2h_pair(float a, float b) {
    return (uint)__half_as_ushort(__float2half(a)) |
           ((uint)__half_as_ushort(__float2half(b)) << 16);
}
__device__ inline float h2f_lo(uint u) { return __half2float(__ushort_as_half((ushort)(u & 0xFFFFu))); }
__device__ inline float h2f_hi(uint u) { return __half2float(__ushort_as_half((ushort)(u >> 16))); }
// split fp32 -> fp16 hi + lo (x ~= hi + lo)
__device__ inline void splitH(float x, ushort& h, ushort& l) {
    __half hh = __float2half(x);
    h = __half_as_ushort(hh);
    l = __half_as_ushort(__float2half(x - __half2float(hh)));
}

// ---------------- bucket histogram ----------------
__global__ __launch_bounds__(256) void hist_bkt(const int* __restrict__ dst,
                                                int* __restrict__ ghist) {
    __shared__ int h[NBKT];
    int t = threadIdx.x;
    for (int i = t; i < NBKT; i += 256) h[i] = 0;
    __syncthreads();
    int beg = blockIdx.x * EPB;
    int end = beg + EPB; if (end > NE) end = NE;
    for (int e = beg + t; e < end; e += 256)
        atomicAdd(&h[dst[e] >> BSH], 1);
    __syncthreads();
    for (int i = t; i < NBKT; i += 256)
        ghist[i * BIN_BLOCKS + blockIdx.x] = h[i];
}

// ---------------- hierarchical scan: phase 1 ----------------
__global__ __launch_bounds__(256) void scan_p1(const int* __restrict__ cnt,
                                               int* __restrict__ bsum, int N) {
    int t = threadIdx.x;
    int base = blockIdx.x * SCAN_CHUNK + t * 4;
    int s = 0;
#pragma unroll
    for (int q = 0; q < 4; q++) {
        int i = base + q;
        if (i < N) s += cnt[i];
    }
    __shared__ int red[4];
#pragma unroll
    for (int off = 32; off; off >>= 1) s += __shfl_down(s, off, 64);
    if ((t & 63) == 0) red[t >> 6] = s;
    __syncthreads();
    if (t == 0) bsum[blockIdx.x] = red[0] + red[1] + red[2] + red[3];
}

// ---------------- phase 2 ----------------
__global__ void scan_p2(int* __restrict__ bsum, int nb) {
    __shared__ int s[128];
    int t = threadIdx.x;
    int v = (t < nb) ? bsum[t] : 0;
    s[t] = v;
    __syncthreads();
    for (int off = 1; off < 128; off <<= 1) {
        int x = s[t];
        int add = (t >= off) ? s[t - off] : 0;
        __syncthreads();
        s[t] = x + add;
        __syncthreads();
    }
    if (t < nb) bsum[t] = s[t] - v;  // exclusive
}

// ---------------- phase 3: in-place exclusive scan ----------------
__global__ __launch_bounds__(256) void scan_p3_plain(int* __restrict__ data,
                                                     const int* __restrict__ bsum, int N) {
    __shared__ int ts[256];
    int t = threadIdx.x;
    int base = blockIdx.x * SCAN_CHUNK + t * 4;
    int c[4];
    int s = 0;
#pragma unroll
    for (int q = 0; q < 4; q++) {
        int i = base + q;
        c[q] = (i < N) ? data[i] : 0;
        s += c[q];
    }
    ts[t] = s;
    __syncthreads();
    for (int off = 1; off < 256; off <<= 1) {
        int x = ts[t];
        int add = (t >= off) ? ts[t - off] : 0;
        __syncthreads();
        ts[t] = x + add;
        __syncthreads();
    }
    int run = bsum[blockIdx.x] + ts[t] - s;
#pragma unroll
    for (int q = 0; q < 4; q++) {
        int i = base + q;
        if (i < N) { data[i] = run; run += c[q]; }
    }
}

// ---------------- bin edges into bucket-segmented records ----------------
__global__ __launch_bounds__(256) void bin_edges(const int* __restrict__ src,
                                                 const int* __restrict__ dst,
                                                 const int* __restrict__ ghist,
                                                 uint* __restrict__ binned) {
    __shared__ int cur[NBKT];
    int t = threadIdx.x;
    for (int i = t; i < NBKT; i += 256) cur[i] = ghist[i * BIN_BLOCKS + blockIdx.x];
    __syncthreads();
    int beg = blockIdx.x * EPB;
    int end = beg + EPB; if (end > NE) end = NE;
    for (int e = beg + t; e < end; e += 256) {
        int d = dst[e];
        int b = d >> BSH;
        int p = atomicAdd(&cur[b], 1);
        binned[p] = ((uint)src[e] << BSH) | (uint)(d & (BKT_NODES - 1));
    }
}

// ---------------- fused: per-bucket degree count + local scan -> rowptr + dinv ----------------
__global__ __launch_bounds__(256) void bucket_rowptr(const uint* __restrict__ binned,
                                                     const int* __restrict__ ghist,
                                                     int* __restrict__ rowptr,
                                                     float* __restrict__ dinv) {
    __shared__ int c[BKT_NODES];
    __shared__ int ts[256];
    int t = threadIdx.x;
    int bkt = blockIdx.x;
    c[t] = 0;
    __syncthreads();
    int beg = ghist[bkt * BIN_BLOCKS];
    int end = (bkt == NBKT - 1) ? NE : ghist[(bkt + 1) * BIN_BLOCKS];
    for (int j = beg + t; j < end; j += 256)
        atomicAdd(&c[binned[j] & (BKT_NODES - 1)], 1);
    __syncthreads();
    int ci = c[t];
    ts[t] = ci;
    __syncthreads();
    for (int off = 1; off < 256; off <<= 1) {
        int x = ts[t];
        int add = (t >= off) ? ts[t - off] : 0;
        __syncthreads();
        ts[t] = x + add;
        __syncthreads();
    }
    int node = bkt * BKT_NODES + t;
    if (node < NN) {
        rowptr[node] = beg + ts[t] - ci;  // exclusive prefix
        dinv[node] = 1.0f / sqrtf((float)(ci + 1));  // +1 self-loop
    }
    if (bkt == 0 && t == 0) rowptr[NN] = NE;
}

// ---------------- per-bucket CSR fill ----------------
__global__ __launch_bounds__(256) void csr_fill(const uint* __restrict__ binned,
                                                const int* __restrict__ ghist,
                                                const int* __restrict__ rowptr,
                                                int* __restrict__ col) {
    __shared__ int fill[BKT_NODES];
    int t = threadIdx.x;
    int bkt = blockIdx.x;
    for (int i = t; i < BKT_NODES; i += 256) fill[i] = 0;
    __syncthreads();
    int beg = ghist[bkt * BIN_BLOCKS];
    int end = (bkt == NBKT - 1) ? NE : ghist[(bkt + 1) * BIN_BLOCKS];
    int base = bkt * BKT_NODES;
    for (int j = beg + t; j < end; j += 256) {
        uint r = binned[j];
        int dl = r & (BKT_NODES - 1);
        int p = rowptr[base + dl] + atomicAdd(&fill[dl], 1);
        col[p] = (int)(r >> BSH);
    }
}

// ---------------- W transpose + fp16 hi/lo split: W[K][128] -> Wt[128][K] ----------------
template <int K>
__global__ __launch_bounds__(256) void wsplit(const float* __restrict__ W,
                                              ushort* __restrict__ Wth,
                                              ushort* __restrict__ Wtl) {
    __shared__ float tile[32][128];
    int t = threadIdx.x;
    int kb = blockIdx.x;
    {
        int k = t >> 3, cq = t & 7;
#pragma unroll
        for (int q = 0; q < 4; q++) {
            float4 v = *(const float4*)&W[(size_t)(kb * 32 + k) * 128 + cq * 16 + q * 4];
            *(float4*)&tile[k][cq * 16 + q * 4] = v;
        }
    }
    __syncthreads();
    {
        int c = t >> 1, g = t & 1;
        ushort hs[16], ls[16];
#pragma unroll
        for (int i = 0; i < 16; i++) splitH(tile[g * 16 + i][c], hs[i], ls[i]);
        uint h[8], lo[8];
#pragma unroll
        for (int i = 0; i < 8; i++) {
            h[i] = (uint)hs[2 * i] | ((uint)hs[2 * i + 1] << 16);
            lo[i] = (uint)ls[2 * i] | ((uint)ls[2 * i + 1] << 16);
        }
        size_t o = (size_t)c * K + kb * 32 + g * 16;
        *(uint4*)&Wth[o] = make_uint4(h[0], h[1], h[2], h[3]);
        *(uint4*)&Wth[o + 8] = make_uint4(h[4], h[5], h[6], h[7]);
        *(uint4*)&Wtl[o] = make_uint4(lo[0], lo[1], lo[2], lo[3]);
        *(uint4*)&Wtl[o + 8] = make_uint4(lo[4], lo[5], lo[6], lo[7]);
    }
}

// ---------------- MFMA GEMM (fp32 input): A via COALESCED+XOR-SWIZZLED global_load_lds ----------------
// A LDS: row-major chunks, chunk c holds global (row=c>>3, kq=(c&7)^(row&7)).
// Staging: 8 lanes cover one row's 128B K-slab (permuted within segment -> coalesced).
// Read: chunk = mrow*8 + (kq ^ (mrow&7)); XOR spreads 8 consecutive rows over 8 bank-slots
// -> 2-way conflict (free). cvt fp32->fp16 after LDS read (VALU idle during MFMA anyway).
template <int K>
__global__ __launch_bounds__(256) void mfma_gemm_f32(const float* __restrict__ X,
                                                     const ushort* __restrict__ Wth,
                                                     const ushort* __restrict__ Wtl,
                                                     const float* __restrict__ dinv,
                                                     uint* __restrict__ Y, int M) {
    __shared__ char smem[32 * 1024];
    char* aF = smem;              // 16 KB fp32 A (128 rows x 8 kq-chunks x 16B)
    char* bH = smem + 16384;      // 8 KB
    char* bL = smem + 24576;      // 8 KB
    int tid = threadIdx.x;
    int w = tid >> 6, l = tid & 63;
    int rowBase = blockIdx.x * 128;

    f32x4 acc[2][8];
#pragma unroll
    for (int mf = 0; mf < 2; mf++)
#pragma unroll
        for (int n = 0; n < 8; n++) acc[mf][n] = (f32x4){0.f, 0.f, 0.f, 0.f};

    int fc = l & 15, fkg = l >> 4;

    for (int kt = 0; kt < K; kt += 32) {
        // ---- A async global->LDS: chunk c -> row=c>>3, kq_g=(c&7)^(row&7); coalesced per row-slab ----
#pragma unroll
        for (int i = 0; i < 4; i++) {
            int cb = (i * 4 + w) * 64;   // wave-uniform chunk base
            int c = cb + l;
            int row = c >> 3;
            int kq = (c & 7) ^ (row & 7);
            int gr = rowBase + row;
            if (gr >= M) gr = 0;  // clamp; epilogue masks these rows
            gload16(&X[(size_t)gr * K + kt + kq * 4], aF + cb * 16);
        }
        // ---- B async global->LDS (kg-plane chunk order; L2-resident) ----
#pragma unroll
        for (int i = 0; i < 2; i++) {
            int cb = (i * 4 + w) * 64;
            int c = cb + l;
            int kg = c >> 7, colb = c & 127;
            size_t go = (size_t)colb * K + kt + kg * 8;
            gload16(&Wth[go], bH + cb * 16);
            gload16(&Wtl[go], bL + cb * 16);
        }
        __syncthreads();

#pragma unroll
        for (int mf = 0; mf < 2; mf++) {
            int mrow = (2 * w + mf) * 16 + fc;
            int sw = mrow & 7;
            f32x4 p0 = *(const f32x4*)(aF + (mrow * 8 + ((2 * fkg) ^ sw)) * 16);
            f32x4 p1 = *(const f32x4*)(aF + (mrow * 8 + ((2 * fkg + 1) ^ sw)) * 16);
            half8 av;
            av[0] = (_Float16)p0[0]; av[1] = (_Float16)p0[1];
            av[2] = (_Float16)p0[2]; av[3] = (_Float16)p0[3];
            av[4] = (_Float16)p1[0]; av[5] = (_Float16)p1[1];
            av[6] = (_Float16)p1[2]; av[7] = (_Float16)p1[3];
#pragma unroll
            for (int n = 0; n < 8; n++) {
                int boff = fkg * 2048 + (16 * n + fc) * 16;
                half8 bh = *(const half8*)(bH + boff);
                half8 bl = *(const half8*)(bL + boff);
                acc[mf][n] = __builtin_amdgcn_mfma_f32_16x16x32_f16(av, bh, acc[mf][n], 0, 0, 0);
                acc[mf][n] = __builtin_amdgcn_mfma_f32_16x16x32_f16(av, bl, acc[mf][n], 0, 0, 0);
            }
        }
        __syncthreads();
    }

    // ---- epilogue: scale by dinv, pack fp16 pairs ----
#pragma unroll
    for (int mf = 0; mf < 2; mf++) {
        float dscale[4];
#pragma unroll
        for (int r = 0; r < 4; r++) {
            int row = rowBase + (2 * w + mf) * 16 + fkg * 4 + r;
            dscale[r] = (row < M) ? dinv[row] : 0.f;
        }
#pragma unroll
        for (int n = 0; n < 8; n++) {
#pragma unroll
            for (int r = 0; r < 4; r++) {
                float val = acc[mf][n][r] * dscale[r];
                float p = __shfl_xor(val, 1, 64);
                int row = rowBase + (2 * w + mf) * 16 + fkg * 4 + r;
                if (!(l & 1) && row < M)
                    Y[(size_t)row * 64 + 8 * n + (fc >> 1)] = f2h_pair(val, p);
            }
        }
    }
}

// ---------------- MFMA GEMM (fp16 input, K=128): all staging via global_load_lds ----------------
__global__ __launch_bounds__(256) void mfma_gemm_f16(const ushort* __restrict__ Xh,
                                                     const ushort* __restrict__ Wth,
                                                     const ushort* __restrict__ Wtl,
                                                     const float* __restrict__ dinv,
                                                     uint* __restrict__ Y, int M) {
    __shared__ char smem[24 * 1024];
    char* aP = smem;
    char* bH = smem + 8192;
    char* bL = smem + 16384;
    int tid = threadIdx.x;
    int w = tid >> 6, l = tid & 63;
    int rowBase = blockIdx.x * 128;

    f32x4 acc[2][8];
#pragma unroll
    for (int mf = 0; mf < 2; mf++)
#pragma unroll
        for (int n = 0; n < 8; n++) acc[mf][n] = (f32x4){0.f, 0.f, 0.f, 0.f};

    int fc = l & 15, fkg = l >> 4;
    int aoff0 = fkg * 2048 + ((2 * w + 0) * 16 + fc) * 16;
    int aoff1 = fkg * 2048 + ((2 * w + 1) * 16 + fc) * 16;

    for (int kt = 0; kt < 128; kt += 32) {
#pragma unroll
        for (int i = 0; i < 2; i++) {
            int cb = (i * 4 + w) * 64;   // wave-uniform
            int c = cb + l;
            int kg = c >> 7, idx = c & 127;
            gload16(&Xh[(size_t)(rowBase + idx) * 128 + kt + kg * 8], aP + cb * 16);
            gload16(&Wth[(size_t)idx * 128 + kt + kg * 8], bH + cb * 16);
            gload16(&Wtl[(size_t)idx * 128 + kt + kg * 8], bL + cb * 16);
        }
        __syncthreads();
        half8 av0 = *(const half8*)(aP + aoff0);
        half8 av1 = *(const half8*)(aP + aoff1);
#pragma unroll
        for (int n = 0; n < 8; n++) {
            int boff = fkg * 2048 + (16 * n + fc) * 16;
            half8 bh = *(const half8*)(bH + boff);
            half8 bl = *(const half8*)(bL + boff);
            acc[0][n] = __builtin_amdgcn_mfma_f32_16x16x32_f16(av0, bh, acc[0][n], 0, 0, 0);
            acc[0][n] = __builtin_amdgcn_mfma_f32_16x16x32_f16(av0, bl, acc[0][n], 0, 0, 0);
            acc[1][n] = __builtin_amdgcn_mfma_f32_16x16x32_f16(av1, bh, acc[1][n], 0, 0, 0);
            acc[1][n] = __builtin_amdgcn_mfma_f32_16x16x32_f16(av1, bl, acc[1][n], 0, 0, 0);
        }
        __syncthreads();
    }

#pragma unroll
    for (int mf = 0; mf < 2; mf++) {
        float dscale[4];
#pragma unroll
        for (int r = 0; r < 4; r++) {
            int row = rowBase + (2 * w + mf) * 16 + fkg * 4 + r;
            dscale[r] = (row < M) ? dinv[row] : 0.f;
        }
#pragma unroll
        for (int n = 0; n < 8; n++) {
#pragma unroll
            for (int r = 0; r < 4; r++) {
                float val = acc[mf][n][r] * dscale[r];
                float p = __shfl_xor(val, 1, 64);
                int row = rowBase + (2 * w + mf) * 16 + fkg * 4 + r;
                if (!(l & 1) && row < M)
                    Y[(size_t)row * 64 + 8 * n + (fc >> 1)] = f2h_pair(val, p);
            }
        }
    }
}

// ---------------- small GEMM N=5 K=128 fp16 in, fused dinv-scale + fp16 pack out ----------------
__global__ __launch_bounds__(256) void gemm_n5h(const uint4* __restrict__ Xh,
                                                const float* __restrict__ W,
                                                const float* __restrict__ dinv,
                                                uint4* __restrict__ hc, int M) {
    __shared__ float wl[640];
    int t = threadIdx.x;
    for (int i = t; i < 640; i += 256) wl[i] = W[i];
    __syncthreads();
    int row = blockIdx.x * 256 + t;
    if (row >= M) return;
    float acc0 = 0.f, acc1 = 0.f, acc2 = 0.f, acc3 = 0.f, acc4 = 0.f;
#pragma unroll
    for (int kq = 0; kq < 16; kq++) {
        uint4 v = Xh[(size_t)row * 16 + kq];
        uint uu[4] = {v.x, v.y, v.z, v.w};
#pragma unroll
        for (int e = 0; e < 4; e++) {
            float x0 = h2f_lo(uu[e]);
            float x1 = h2f_hi(uu[e]);
            int k = kq * 8 + e * 2;
            acc0 = fmaf(x0, wl[k * 5 + 0], acc0); acc0 = fmaf(x1, wl[k * 5 + 5], acc0);
            acc1 = fmaf(x0, wl[k * 5 + 1], acc1); acc1 = fmaf(x1, wl[k * 5 + 6], acc1);
            acc2 = fmaf(x0, wl[k * 5 + 2], acc2); acc2 = fmaf(x1, wl[k * 5 + 7], acc2);
            acc3 = fmaf(x0, wl[k * 5 + 3], acc3); acc3 = fmaf(x1, wl[k * 5 + 8], acc3);
            acc4 = fmaf(x0, wl[k * 5 + 4], acc4); acc4 = fmaf(x1, wl[k * 5 + 9], acc4);
        }
    }
    float di = dinv[row];
    hc[row] = make_uint4(f2h_pair(acc0 * di, acc1 * di),
                         f2h_pair(acc2 * di, acc3 * di),
                         f2h_pair(acc4 * di, 0.f), 0u);
}

#define ACC8H(v)                              \
    a0 += h2f_lo(v.x); a1 += h2f_hi(v.x);     \
    a2 += h2f_lo(v.y); a3 += h2f_hi(v.y);     \
    a4 += h2f_lo(v.z); a5 += h2f_hi(v.z);     \
    a6 += h2f_lo(v.w); a7 += h2f_hi(v.w);

// ---------------- CSR aggregation, dim 128 (fp16): wave/node, out = fp16 rows ----------------
__global__ __launch_bounds__(256) void agg128_v3(const uint4* __restrict__ hb4,
                                                 const int* __restrict__ rowptr,
                                                 const int* __restrict__ col,
                                                 const float* __restrict__ dinv,
                                                 const float* __restrict__ bias,
                                                 uint4* __restrict__ out, int N, int do_relu) {
    int wave = threadIdx.x >> 6;
    int lane = threadIdx.x & 63;
    int node = blockIdx.x * 4 + wave;
    if (node >= N) return;
    int g = lane >> 4;    // edge slot 0..3
    int q = lane & 15;    // dim-octet: dims [q*8, q*8+8)
    int beg = rowptr[node], end = rowptr[node + 1];
    float a0 = 0.f, a1 = 0.f, a2 = 0.f, a3 = 0.f, a4 = 0.f, a5 = 0.f, a6 = 0.f, a7 = 0.f;

    int j = beg;
    for (; j + 16 <= end; j += 16) {
        int s0 = col[j + g];
        int s1 = col[j + 4 + g];
        int s2 = col[j + 8 + g];
        int s3 = col[j + 12 + g];
        uint4 v0 = hb4[(size_t)s0 * 16 + q];
        uint4 v1 = hb4[(size_t)s1 * 16 + q];
        uint4 v2 = hb4[(size_t)s2 * 16 + q];
        uint4 v3 = hb4[(size_t)s3 * 16 + q];
        ACC8H(v0); ACC8H(v1); ACC8H(v2); ACC8H(v3);
    }
    if (j + 8 <= end) {
        int s0 = col[j + g];
        int s1 = col[j + 4 + g];
        uint4 v0 = hb4[(size_t)s0 * 16 + q];
        uint4 v1 = hb4[(size_t)s1 * 16 + q];
        ACC8H(v0); ACC8H(v1);
        j += 8;
    }
    if (j < end) {
        int jj0 = j + g, jj1 = j + 4 + g;
        bool p0 = jj0 < end, p1 = jj1 < end;
        int s0 = p0 ? col[jj0] : node;
        int s1 = p1 ? col[jj1] : node;
        uint4 v0 = hb4[(size_t)s0 * 16 + q];
        uint4 v1 = hb4[(size_t)s1 * 16 + q];
        if (!p0) v0 = make_uint4(0u, 0u, 0u, 0u);
        if (!p1) v1 = make_uint4(0u, 0u, 0u, 0u);
        ACC8H(v0); ACC8H(v1);
    }
#pragma unroll
    for (int off = 16; off <= 32; off <<= 1) {
        a0 += __shfl_xor(a0, off, 64);
        a1 += __shfl_xor(a1, off, 64);
        a2 += __shfl_xor(a2, off, 64);
        a3 += __shfl_xor(a3, off, 64);
        a4 += __shfl_xor(a4, off, 64);
        a5 += __shfl_xor(a5, off, 64);
        a6 += __shfl_xor(a6, off, 64);
        a7 += __shfl_xor(a7, off, 64);
    }
    if (g == 0) {
        uint4 vs = hb4[(size_t)node * 16 + q];  // self term (pre-scaled)
        ACC8H(vs);
        float di = dinv[node];
        const float4* bias4 = (const float4*)bias;
        float4 bb0 = bias4[q * 2], bb1 = bias4[q * 2 + 1];
        float o0 = a0 * di + bb0.x, o1 = a1 * di + bb0.y;
        float o2 = a2 * di + bb0.z, o3 = a3 * di + bb0.w;
        float o4 = a4 * di + bb1.x, o5 = a5 * di + bb1.y;
        float o6 = a6 * di + bb1.z, o7 = a7 * di + bb1.w;
        if (do_relu) {
            o0 = fmaxf(o0, 0.f); o1 = fmaxf(o1, 0.f);
            o2 = fmaxf(o2, 0.f); o3 = fmaxf(o3, 0.f);
            o4 = fmaxf(o4, 0.f); o5 = fmaxf(o5, 0.f);
            o6 = fmaxf(o6, 0.f); o7 = fmaxf(o7, 0.f);
        }
        out[(size_t)node * 16 + q] =
            make_uint4(f2h_pair(o0, o1), f2h_pair(o2, o3), f2h_pair(o4, o5), f2h_pair(o6, o7));
    }
}

// ---------------- CSR aggregation, dim 5 (fp16 packed rows): thread per node ----------------
__global__ void agg5_v2(const uint4* __restrict__ hc, const int* __restrict__ rowptr,
                        const int* __restrict__ col, const float* __restrict__ dinv,
                        const float* __restrict__ b3, float* __restrict__ out, int N) {
    int node = blockIdx.x * 256 + threadIdx.x;
    if (node >= N) return;
    float a0 = 0.f, a1 = 0.f, a2 = 0.f, a3 = 0.f, a4 = 0.f;
    int beg = rowptr[node], end = rowptr[node + 1];
#pragma unroll 2
    for (int j = beg; j < end; ++j) {
        uint4 v = hc[col[j]];
        a0 += h2f_lo(v.x); a1 += h2f_hi(v.x);
        a2 += h2f_lo(v.y); a3 += h2f_hi(v.y);
        a4 += h2f_lo(v.z);
    }
    uint4 vs = hc[node];
    a0 += h2f_lo(vs.x); a1 += h2f_hi(vs.x);
    a2 += h2f_lo(vs.y); a3 += h2f_hi(vs.y);
    a4 += h2f_lo(vs.z);
    float di = dinv[node];
    out[node * 5 + 0] = a0 * di + b3[0];
    out[node * 5 + 1] = a1 * di + b3[1];
    out[node * 5 + 2] = a2 * di + b3[2];
    out[node * 5 + 3] = a3 * di + b3[3];
    out[node * 5 + 4] = a4 * di + b3[4];
}

static inline size_t align512(size_t x) { return (x + 511) & ~(size_t)511; }

extern "C" void kernel_launch(void* const* d_in, const int* in_sizes, int n_in,
                              void* d_out, int out_size, void* d_ws, size_t ws_size,
                              hipStream_t stream) {
    const float* x  = (const float*)d_in[0];
    const int* ei   = (const int*)d_in[1];
    const float* W1 = (const float*)d_in[2];
    const float* b1 = (const float*)d_in[3];
    const float* W2 = (const float*)d_in[4];
    const float* b2 = (const float*)d_in[5];
    const float* W3 = (const float*)d_in[6];
    const float* b3 = (const float*)d_in[7];
    const int* src = ei;
    const int* dst = ei + NE;

    char* ws = (char*)d_ws;
    size_t off = 0;
    int* rowptr = (int*)(ws + off);     off += align512((size_t)(NN + 1) * 4);
    float* dinv = (float*)(ws + off);   off += align512((size_t)NN * 4);
    int* bsum = (int*)(ws + off);       off += align512((size_t)128 * 4);
    int* ghist = (int*)(ws + off);      off += align512((size_t)GH * 4);
    ushort* wt1h = (ushort*)(ws + off); off += align512((size_t)128 * 384 * 2);
    ushort* wt1l = (ushort*)(ws + off); off += align512((size_t)128 * 384 * 2);
    ushort* wt2h = (ushort*)(ws + off); off += align512((size_t)128 * 128 * 2);
    ushort* wt2l = (ushort*)(ws + off); off += align512((size_t)128 * 128 * 2);
    int* col = (int*)(ws + off);        off += align512((size_t)NE * 4);
    uint* hb = (uint*)(ws + off);       off += align512((size_t)NN * 64 * 4);   // fp16 dinv*h (packed)
    char* bufF = (char*)(ws + off);     off += align512((size_t)NN * 128 * 4);  // fp16 agg out (oversized: OOB-tile reads stay in ws)
    uint4* hc = (uint4*)(ws + off);     off += align512((size_t)NN * 16);       // packed fp16 dinv*h5
    uint* binned = (uint*)bufF;  // alias: binned dead before bufF's first write
    (void)ws_size;

    // ---- W transpose + fp16 hi/lo split ----
    wsplit<384><<<12, 256, 0, stream>>>(W1, wt1h, wt1l);
    wsplit<128><<<4, 256, 0, stream>>>(W2, wt2h, wt2l);

    // ---- build CSR (by dst) + dinv, bucket-sorted for write locality ----
    hist_bkt<<<BIN_BLOCKS, 256, 0, stream>>>(dst, ghist);
    {
        int nb = (GH + SCAN_CHUNK - 1) / SCAN_CHUNK;  // 98
        scan_p1<<<nb, 256, 0, stream>>>(ghist, bsum, GH);
        scan_p2<<<1, 128, 0, stream>>>(bsum, nb);
        scan_p3_plain<<<nb, 256, 0, stream>>>(ghist, bsum, GH);
    }
    bin_edges<<<BIN_BLOCKS, 256, 0, stream>>>(src, dst, ghist, binned);
    bucket_rowptr<<<NBKT, 256, 0, stream>>>(binned, ghist, rowptr, dinv);
    csr_fill<<<NBKT, 256, 0, stream>>>(binned, ghist, rowptr, col);

    int gemm_blocks = (NN + 127) / 128;  // 782
    // ---- layer 1 ----
    mfma_gemm_f32<384><<<gemm_blocks, 256, 0, stream>>>(x, wt1h, wt1l, dinv, hb, NN);
    agg128_v3<<<(NN + 3) / 4, 256, 0, stream>>>((const uint4*)hb, rowptr, col, dinv, b1,
                                                (uint4*)bufF, NN, 1);
    // ---- layer 2 ----
    mfma_gemm_f16<<<gemm_blocks, 256, 0, stream>>>((const ushort*)bufF, wt2h, wt2l, dinv, hb, NN);
    agg128_v3<<<(NN + 3) / 4, 256, 0, stream>>>((const uint4*)hb, rowptr, col, dinv, b2,
                                                (uint4*)bufF, NN, 1);
    // ---- layer 3 ----
    gemm_n5h<<<(NN + 255) / 256, 256, 0, stream>>>((const uint4*)bufF, W3, dinv, hc, NN);
    agg5_v2<<<(NN + 255) / 256, 256, 0, stream>>>(hc, rowptr, col, dinv, b3, (float*)d_out, NN);
}

// Round 13
// 421.073 us; speedup vs baseline: 1.0953x; 1.0499x over previous
//
#include <hip/hip_runtime.h>
#include <hip/hip_fp16.h>

#define NN 100000
#define NE 3200000
#define SCAN_CHUNK 1024

// bucket sort params
#define BSH 8
#define BKT_NODES 256                       // 1 << BSH
#define NBKT ((NN + BKT_NODES - 1) / BKT_NODES)   // 391
#define BIN_BLOCKS 256
#define EPB ((NE + BIN_BLOCKS - 1) / BIN_BLOCKS)  // 12500
#define GH (NBKT * BIN_BLOCKS)                    // 100096
#define REC_CAP 9216                              // per-bucket record cap (mean 8184, sigma~90)

typedef unsigned int uint;
typedef unsigned short ushort;
typedef __attribute__((ext_vector_type(8))) _Float16 half8;
typedef __attribute__((ext_vector_type(4))) float f32x4;

// async global->LDS, 16B per lane; dest = wave-uniform base + lane*16
__device__ inline void gload16(const void* g, void* l) {
    __builtin_amdgcn_global_load_lds(
        (const __attribute__((address_space(1))) void*)g,
        (__attribute__((address_space(3))) void*)l, 16, 0, 0);
}

// fp16 helpers (RNE via v_cvt_f16_f32)
__device__ inline uint f2h_pair(float a, float b) {
    return (uint)__half_as_ushort(__float2half(a)) |
           ((uint)__half_as_ushort(__float2half(b)) << 16);
}
__device__ inline float h2f_lo(uint u) { return __half2float(__ushort_as_half((ushort)(u & 0xFFFFu))); }
__device__ inline float h2f_hi(uint u) { return __half2float(__ushort_as_half((ushort)(u >> 16))); }
// split fp32 -> fp16 hi + lo (x ~= hi + lo)
__device__ inline void splitH(float x, ushort& h, ushort& l) {
    __half hh = __float2half(x);
    h = __half_as_ushort(hh);
    l = __half_as_ushort(__float2half(x - __half2float(hh)));
}

// ---------------- bucket histogram ----------------
__global__ __launch_bounds__(256) void hist_bkt(const int* __restrict__ dst,
                                                int* __restrict__ ghist) {
    __shared__ int h[NBKT];
    int t = threadIdx.x;
    for (int i = t; i < NBKT; i += 256) h[i] = 0;
    __syncthreads();
    int beg = blockIdx.x * EPB;
    int end = beg + EPB; if (end > NE) end = NE;
    for (int e = beg + t; e < end; e += 256)
        atomicAdd(&h[dst[e] >> BSH], 1);
    __syncthreads();
    for (int i = t; i < NBKT; i += 256)
        ghist[i * BIN_BLOCKS + blockIdx.x] = h[i];
}

// ---------------- hierarchical scan: phase 1 ----------------
__global__ __launch_bounds__(256) void scan_p1(const int* __restrict__ cnt,
                                               int* __restrict__ bsum, int N) {
    int t = threadIdx.x;
    int base = blockIdx.x * SCAN_CHUNK + t * 4;
    int s = 0;
#pragma unroll
    for (int q = 0; q < 4; q++) {
        int i = base + q;
        if (i < N) s += cnt[i];
    }
    __shared__ int red[4];
#pragma unroll
    for (int off = 32; off; off >>= 1) s += __shfl_down(s, off, 64);
    if ((t & 63) == 0) red[t >> 6] = s;
    __syncthreads();
    if (t == 0) bsum[blockIdx.x] = red[0] + red[1] + red[2] + red[3];
}

// ---------------- phase 2 ----------------
__global__ void scan_p2(int* __restrict__ bsum, int nb) {
    __shared__ int s[128];
    int t = threadIdx.x;
    int v = (t < nb) ? bsum[t] : 0;
    s[t] = v;
    __syncthreads();
    for (int off = 1; off < 128; off <<= 1) {
        int x = s[t];
        int add = (t >= off) ? s[t - off] : 0;
        __syncthreads();
        s[t] = x + add;
        __syncthreads();
    }
    if (t < nb) bsum[t] = s[t] - v;  // exclusive
}

// ---------------- phase 3: in-place exclusive scan ----------------
__global__ __launch_bounds__(256) void scan_p3_plain(int* __restrict__ data,
                                                     const int* __restrict__ bsum, int N) {
    __shared__ int ts[256];
    int t = threadIdx.x;
    int base = blockIdx.x * SCAN_CHUNK + t * 4;
    int c[4];
    int s = 0;
#pragma unroll
    for (int q = 0; q < 4; q++) {
        int i = base + q;
        c[q] = (i < N) ? data[i] : 0;
        s += c[q];
    }
    ts[t] = s;
    __syncthreads();
    for (int off = 1; off < 256; off <<= 1) {
        int x = ts[t];
        int add = (t >= off) ? ts[t - off] : 0;
        __syncthreads();
        ts[t] = x + add;
        __syncthreads();
    }
    int run = bsum[blockIdx.x] + ts[t] - s;
#pragma unroll
    for (int q = 0; q < 4; q++) {
        int i = base + q;
        if (i < N) { data[i] = run; run += c[q]; }
    }
}

// ---------------- bin edges into bucket-segmented records ----------------
__global__ __launch_bounds__(256) void bin_edges(const int* __restrict__ src,
                                                 const int* __restrict__ dst,
                                                 const int* __restrict__ ghist,
                                                 uint* __restrict__ binned) {
    __shared__ int cur[NBKT];
    int t = threadIdx.x;
    for (int i = t; i < NBKT; i += 256) cur[i] = ghist[i * BIN_BLOCKS + blockIdx.x];
    __syncthreads();
    int beg = blockIdx.x * EPB;
    int end = beg + EPB; if (end > NE) end = NE;
    for (int e = beg + t; e < end; e += 256) {
        int d = dst[e];
        int b = d >> BSH;
        int p = atomicAdd(&cur[b], 1);
        binned[p] = ((uint)src[e] << BSH) | (uint)(d & (BKT_NODES - 1));
    }
}

// ---------------- fused per-bucket: count + scan -> rowptr/dinv, then CSR fill from LDS ----------------
__global__ __launch_bounds__(256) void bucket_csr(const uint* __restrict__ binned,
                                                  const int* __restrict__ ghist,
                                                  int* __restrict__ rowptr,
                                                  float* __restrict__ dinv,
                                                  int* __restrict__ col) {
    __shared__ uint rec[REC_CAP];
    __shared__ int c[BKT_NODES];
    __shared__ int ts[256];
    int t = threadIdx.x;
    int bkt = blockIdx.x;
    int beg = ghist[bkt * BIN_BLOCKS];
    int end = (bkt == NBKT - 1) ? NE : ghist[(bkt + 1) * BIN_BLOCKS];
    int n = end - beg;
    bool fits = (n <= REC_CAP);  // block-uniform
    c[t] = 0;
    __syncthreads();
    if (fits) {
        for (int i = t; i < n; i += 256) {
            uint r = binned[beg + i];
            rec[i] = r;
            atomicAdd(&c[r & (BKT_NODES - 1)], 1);
        }
    } else {
        for (int j = beg + t; j < end; j += 256)
            atomicAdd(&c[binned[j] & (BKT_NODES - 1)], 1);
    }
    __syncthreads();
    int ci = c[t];
    ts[t] = ci;
    __syncthreads();
    for (int off = 1; off < 256; off <<= 1) {
        int x = ts[t];
        int add = (t >= off) ? ts[t - off] : 0;
        __syncthreads();
        ts[t] = x + add;
        __syncthreads();
    }
    int excl = ts[t] - ci;
    int node = bkt * BKT_NODES + t;
    if (node < NN) {
        rowptr[node] = beg + excl;
        dinv[node] = 1.0f / sqrtf((float)(ci + 1));  // +1 self-loop
    }
    if (bkt == 0 && t == 0) rowptr[NN] = NE;
    __syncthreads();
    c[t] = beg + excl;  // repurpose as fill cursor
    __syncthreads();
    if (fits) {
        for (int i = t; i < n; i += 256) {
            uint r = rec[i];
            int p = atomicAdd(&c[r & (BKT_NODES - 1)], 1);
            col[p] = (int)(r >> BSH);
        }
    } else {
        for (int j = beg + t; j < end; j += 256) {
            uint r = binned[j];
            int p = atomicAdd(&c[r & (BKT_NODES - 1)], 1);
            col[p] = (int)(r >> BSH);
        }
    }
}

// ---------------- W transpose + fp16 hi/lo split: W[K][128] -> Wt[128][K] ----------------
template <int K>
__global__ __launch_bounds__(256) void wsplit(const float* __restrict__ W,
                                              ushort* __restrict__ Wth,
                                              ushort* __restrict__ Wtl) {
    __shared__ float tile[32][128];
    int t = threadIdx.x;
    int kb = blockIdx.x;
    {
        int k = t >> 3, cq = t & 7;
#pragma unroll
        for (int q = 0; q < 4; q++) {
            float4 v = *(const float4*)&W[(size_t)(kb * 32 + k) * 128 + cq * 16 + q * 4];
            *(float4*)&tile[k][cq * 16 + q * 4] = v;
        }
    }
    __syncthreads();
    {
        int c = t >> 1, g = t & 1;
        ushort hs[16], ls[16];
#pragma unroll
        for (int i = 0; i < 16; i++) splitH(tile[g * 16 + i][c], hs[i], ls[i]);
        uint h[8], lo[8];
#pragma unroll
        for (int i = 0; i < 8; i++) {
            h[i] = (uint)hs[2 * i] | ((uint)hs[2 * i + 1] << 16);
            lo[i] = (uint)ls[2 * i] | ((uint)ls[2 * i + 1] << 16);
        }
        size_t o = (size_t)c * K + kb * 32 + g * 16;
        *(uint4*)&Wth[o] = make_uint4(h[0], h[1], h[2], h[3]);
        *(uint4*)&Wth[o + 8] = make_uint4(h[4], h[5], h[6], h[7]);
        *(uint4*)&Wtl[o] = make_uint4(lo[0], lo[1], lo[2], lo[3]);
        *(uint4*)&Wtl[o + 8] = make_uint4(lo[4], lo[5], lo[6], lo[7]);
    }
}

// ---------------- MFMA GEMM (fp32 input): reg-prefetch A (r9 structure) ----------------
// A: reg-load one K-step ahead (HBM latency hides under MFMA phase), cvt fp16, ds_write
// to kg-plane-major LDS (plane = kg*2048 + idx*16 -> conflict-free b128 reads).
// B: async global_load_lds (L2-resident Wt planes).
template <int K>
__global__ __launch_bounds__(256) void mfma_gemm_f32(const float* __restrict__ X,
                                                     const ushort* __restrict__ Wth,
                                                     const ushort* __restrict__ Wtl,
                                                     const float* __restrict__ dinv,
                                                     uint* __restrict__ Y, int M) {
    __shared__ char smem[24 * 1024];
    char* aP = smem;              // 8 KB: 4 kg-planes x 128 rows x 16B (fp16)
    char* bH = smem + 8192;       // 8 KB
    char* bL = smem + 16384;      // 8 KB
    int tid = threadIdx.x;
    int w = tid >> 6, l = tid & 63;
    int rowBase = blockIdx.x * 128;

    f32x4 acc[2][8];
#pragma unroll
    for (int mf = 0; mf < 2; mf++)
#pragma unroll
        for (int n = 0; n < 8; n++) acc[mf][n] = (f32x4){0.f, 0.f, 0.f, 0.f};

    // A staging: thread t -> row t>>1, k-half t&1 (16 fp32)
    int sRow = tid >> 1, sKp = tid & 1;
    int gRow = rowBase + sRow;
    bool rowOK = gRow < M;
    size_t aBase = (size_t)(rowOK ? gRow : 0) * K + sKp * 16;

    float4 a0, a1, a2, a3;
    a0 = a1 = a2 = a3 = make_float4(0.f, 0.f, 0.f, 0.f);
    if (rowOK) {
        a0 = *(const float4*)&X[aBase];
        a1 = *(const float4*)&X[aBase + 4];
        a2 = *(const float4*)&X[aBase + 8];
        a3 = *(const float4*)&X[aBase + 12];
    }

    int fc = l & 15, fkg = l >> 4;
    int aoff0 = fkg * 2048 + ((2 * w + 0) * 16 + fc) * 16;
    int aoff1 = fkg * 2048 + ((2 * w + 1) * 16 + fc) * 16;

    for (int kt = 0; kt < K; kt += 32) {
        // ---- B async global->LDS first (L2 latency hides under A cvt) ----
#pragma unroll
        for (int i = 0; i < 2; i++) {
            int cb = (i * 4 + w) * 64;   // wave-uniform
            int c = cb + l;
            int kg = c >> 7, colb = c & 127;
            size_t go = (size_t)colb * K + kt + kg * 8;
            gload16(&Wth[go], bH + cb * 16);
            gload16(&Wtl[go], bL + cb * 16);
        }
        // ---- cvt A regs -> fp16 plane ----
        {
            float v[16] = {a0.x, a0.y, a0.z, a0.w, a1.x, a1.y, a1.z, a1.w,
                           a2.x, a2.y, a2.z, a2.w, a3.x, a3.y, a3.z, a3.w};
            uint hh[8];
#pragma unroll
            for (int i = 0; i < 8; i++) hh[i] = f2h_pair(v[2 * i], v[2 * i + 1]);
            *(uint4*)(aP + (2 * sKp) * 2048 + sRow * 16) = make_uint4(hh[0], hh[1], hh[2], hh[3]);
            *(uint4*)(aP + (2 * sKp + 1) * 2048 + sRow * 16) = make_uint4(hh[4], hh[5], hh[6], hh[7]);
        }
        __syncthreads();

        // ---- prefetch next A tile (HBM latency hides under MFMA) ----
        if (kt + 32 < K && rowOK) {
            size_t nb = aBase + kt + 32;
            a0 = *(const float4*)&X[nb];
            a1 = *(const float4*)&X[nb + 4];
            a2 = *(const float4*)&X[nb + 8];
            a3 = *(const float4*)&X[nb + 12];
        }

        half8 av0 = *(const half8*)(aP + aoff0);
        half8 av1 = *(const half8*)(aP + aoff1);
#pragma unroll
        for (int n = 0; n < 8; n++) {
            int boff = fkg * 2048 + (16 * n + fc) * 16;
            half8 bh = *(const half8*)(bH + boff);
            half8 bl = *(const half8*)(bL + boff);
            acc[0][n] = __builtin_amdgcn_mfma_f32_16x16x32_f16(av0, bh, acc[0][n], 0, 0, 0);
            acc[0][n] = __builtin_amdgcn_mfma_f32_16x16x32_f16(av0, bl, acc[0][n], 0, 0, 0);
            acc[1][n] = __builtin_amdgcn_mfma_f32_16x16x32_f16(av1, bh, acc[1][n], 0, 0, 0);
            acc[1][n] = __builtin_amdgcn_mfma_f32_16x16x32_f16(av1, bl, acc[1][n], 0, 0, 0);
        }
        __syncthreads();
    }

    // ---- epilogue: scale by dinv, pack fp16 pairs ----
#pragma unroll
    for (int mf = 0; mf < 2; mf++) {
        float dscale[4];
#pragma unroll
        for (int r = 0; r < 4; r++) {
            int row = rowBase + (2 * w + mf) * 16 + fkg * 4 + r;
            dscale[r] = (row < M) ? dinv[row] : 0.f;
        }
#pragma unroll
        for (int n = 0; n < 8; n++) {
#pragma unroll
            for (int r = 0; r < 4; r++) {
                float val = acc[mf][n][r] * dscale[r];
                float p = __shfl_xor(val, 1, 64);
                int row = rowBase + (2 * w + mf) * 16 + fkg * 4 + r;
                if (!(l & 1) && row < M)
                    Y[(size_t)row * 64 + 8 * n + (fc >> 1)] = f2h_pair(val, p);
            }
        }
    }
}

// ---------------- MFMA GEMM (fp16 input, K=128): all staging via global_load_lds ----------------
__global__ __launch_bounds__(256) void mfma_gemm_f16(const ushort* __restrict__ Xh,
                                                     const ushort* __restrict__ Wth,
                                                     const ushort* __restrict__ Wtl,
                                                     const float* __restrict__ dinv,
                                                     uint* __restrict__ Y, int M) {
    __shared__ char smem[24 * 1024];
    char* aP = smem;
    char* bH = smem + 8192;
    char* bL = smem + 16384;
    int tid = threadIdx.x;
    int w = tid >> 6, l = tid & 63;
    int rowBase = blockIdx.x * 128;

    f32x4 acc[2][8];
#pragma unroll
    for (int mf = 0; mf < 2; mf++)
#pragma unroll
        for (int n = 0; n < 8; n++) acc[mf][n] = (f32x4){0.f, 0.f, 0.f, 0.f};

    int fc = l & 15, fkg = l >> 4;
    int aoff0 = fkg * 2048 + ((2 * w + 0) * 16 + fc) * 16;
    int aoff1 = fkg * 2048 + ((2 * w + 1) * 16 + fc) * 16;

    for (int kt = 0; kt < 128; kt += 32) {
#pragma unroll
        for (int i = 0; i < 2; i++) {
            int cb = (i * 4 + w) * 64;   // wave-uniform
            int c = cb + l;
            int kg = c >> 7, idx = c & 127;
            gload16(&Xh[(size_t)(rowBase + idx) * 128 + kt + kg * 8], aP + cb * 16);
            gload16(&Wth[(size_t)idx * 128 + kt + kg * 8], bH + cb * 16);
            gload16(&Wtl[(size_t)idx * 128 + kt + kg * 8], bL + cb * 16);
        }
        __syncthreads();
        half8 av0 = *(const half8*)(aP + aoff0);
        half8 av1 = *(const half8*)(aP + aoff1);
#pragma unroll
        for (int n = 0; n < 8; n++) {
            int boff = fkg * 2048 + (16 * n + fc) * 16;
            half8 bh = *(const half8*)(bH + boff);
            half8 bl = *(const half8*)(bL + boff);
            acc[0][n] = __builtin_amdgcn_mfma_f32_16x16x32_f16(av0, bh, acc[0][n], 0, 0, 0);
            acc[0][n] = __builtin_amdgcn_mfma_f32_16x16x32_f16(av0, bl, acc[0][n], 0, 0, 0);
            acc[1][n] = __builtin_amdgcn_mfma_f32_16x16x32_f16(av1, bh, acc[1][n], 0, 0, 0);
            acc[1][n] = __builtin_amdgcn_mfma_f32_16x16x32_f16(av1, bl, acc[1][n], 0, 0, 0);
        }
        __syncthreads();
    }

#pragma unroll
    for (int mf = 0; mf < 2; mf++) {
        float dscale[4];
#pragma unroll
        for (int r = 0; r < 4; r++) {
            int row = rowBase + (2 * w + mf) * 16 + fkg * 4 + r;
            dscale[r] = (row < M) ? dinv[row] : 0.f;
        }
#pragma unroll
        for (int n = 0; n < 8; n++) {
#pragma unroll
            for (int r = 0; r < 4; r++) {
                float val = acc[mf][n][r] * dscale[r];
                float p = __shfl_xor(val, 1, 64);
                int row = rowBase + (2 * w + mf) * 16 + fkg * 4 + r;
                if (!(l & 1) && row < M)
                    Y[(size_t)row * 64 + 8 * n + (fc >> 1)] = f2h_pair(val, p);
            }
        }
    }
}

// ---------------- small GEMM N=5 K=128 fp16 in, fused dinv-scale + fp16 pack out ----------------
__global__ __launch_bounds__(256) void gemm_n5h(const uint4* __restrict__ Xh,
                                                const float* __restrict__ W,
                                                const float* __restrict__ dinv,
                                                uint4* __restrict__ hc, int M) {
    __shared__ float wl[640];
    int t = threadIdx.x;
    for (int i = t; i < 640; i += 256) wl[i] = W[i];
    __syncthreads();
    int row = blockIdx.x * 256 + t;
    if (row >= M) return;
    float acc0 = 0.f, acc1 = 0.f, acc2 = 0.f, acc3 = 0.f, acc4 = 0.f;
#pragma unroll
    for (int kq = 0; kq < 16; kq++) {
        uint4 v = Xh[(size_t)row * 16 + kq];
        uint uu[4] = {v.x, v.y, v.z, v.w};
#pragma unroll
        for (int e = 0; e < 4; e++) {
            float x0 = h2f_lo(uu[e]);
            float x1 = h2f_hi(uu[e]);
            int k = kq * 8 + e * 2;
            acc0 = fmaf(x0, wl[k * 5 + 0], acc0); acc0 = fmaf(x1, wl[k * 5 + 5], acc0);
            acc1 = fmaf(x0, wl[k * 5 + 1], acc1); acc1 = fmaf(x1, wl[k * 5 + 6], acc1);
            acc2 = fmaf(x0, wl[k * 5 + 2], acc2); acc2 = fmaf(x1, wl[k * 5 + 7], acc2);
            acc3 = fmaf(x0, wl[k * 5 + 3], acc3); acc3 = fmaf(x1, wl[k * 5 + 8], acc3);
            acc4 = fmaf(x0, wl[k * 5 + 4], acc4); acc4 = fmaf(x1, wl[k * 5 + 9], acc4);
        }
    }
    float di = dinv[row];
    hc[row] = make_uint4(f2h_pair(acc0 * di, acc1 * di),
                         f2h_pair(acc2 * di, acc3 * di),
                         f2h_pair(acc4 * di, 0.f), 0u);
}

#define ACC8H(v)                              \
    a0 += h2f_lo(v.x); a1 += h2f_hi(v.x);     \
    a2 += h2f_lo(v.y); a3 += h2f_hi(v.y);     \
    a4 += h2f_lo(v.z); a5 += h2f_hi(v.z);     \
    a6 += h2f_lo(v.w); a7 += h2f_hi(v.w);

// ---------------- CSR aggregation, dim 128 (fp16): wave/node, out = fp16 rows ----------------
__global__ __launch_bounds__(256) void agg128_v3(const uint4* __restrict__ hb4,
                                                 const int* __restrict__ rowptr,
                                                 const int* __restrict__ col,
                                                 const float* __restrict__ dinv,
                                                 const float* __restrict__ bias,
                                                 uint4* __restrict__ out, int N, int do_relu) {
    int wave = threadIdx.x >> 6;
    int lane = threadIdx.x & 63;
    int node = blockIdx.x * 4 + wave;
    if (node >= N) return;
    int g = lane >> 4;    // edge slot 0..3
    int q = lane & 15;    // dim-octet: dims [q*8, q*8+8)
    int beg = rowptr[node], end = rowptr[node + 1];
    float a0 = 0.f, a1 = 0.f, a2 = 0.f, a3 = 0.f, a4 = 0.f, a5 = 0.f, a6 = 0.f, a7 = 0.f;

    int j = beg;
    for (; j + 16 <= end; j += 16) {
        int s0 = col[j + g];
        int s1 = col[j + 4 + g];
        int s2 = col[j + 8 + g];
        int s3 = col[j + 12 + g];
        uint4 v0 = hb4[(size_t)s0 * 16 + q];
        uint4 v1 = hb4[(size_t)s1 * 16 + q];
        uint4 v2 = hb4[(size_t)s2 * 16 + q];
        uint4 v3 = hb4[(size_t)s3 * 16 + q];
        ACC8H(v0); ACC8H(v1); ACC8H(v2); ACC8H(v3);
    }
    if (j + 8 <= end) {
        int s0 = col[j + g];
        int s1 = col[j + 4 + g];
        uint4 v0 = hb4[(size_t)s0 * 16 + q];
        uint4 v1 = hb4[(size_t)s1 * 16 + q];
        ACC8H(v0); ACC8H(v1);
        j += 8;
    }
    if (j < end) {
        int jj0 = j + g, jj1 = j + 4 + g;
        bool p0 = jj0 < end, p1 = jj1 < end;
        int s0 = p0 ? col[jj0] : node;
        int s1 = p1 ? col[jj1] : node;
        uint4 v0 = hb4[(size_t)s0 * 16 + q];
        uint4 v1 = hb4[(size_t)s1 * 16 + q];
        if (!p0) v0 = make_uint4(0u, 0u, 0u, 0u);
        if (!p1) v1 = make_uint4(0u, 0u, 0u, 0u);
        ACC8H(v0); ACC8H(v1);
    }
#pragma unroll
    for (int off = 16; off <= 32; off <<= 1) {
        a0 += __shfl_xor(a0, off, 64);
        a1 += __shfl_xor(a1, off, 64);
        a2 += __shfl_xor(a2, off, 64);
        a3 += __shfl_xor(a3, off, 64);
        a4 += __shfl_xor(a4, off, 64);
        a5 += __shfl_xor(a5, off, 64);
        a6 += __shfl_xor(a6, off, 64);
        a7 += __shfl_xor(a7, off, 64);
    }
    if (g == 0) {
        uint4 vs = hb4[(size_t)node * 16 + q];  // self term (pre-scaled)
        ACC8H(vs);
        float di = dinv[node];
        const float4* bias4 = (const float4*)bias;
        float4 bb0 = bias4[q * 2], bb1 = bias4[q * 2 + 1];
        float o0 = a0 * di + bb0.x, o1 = a1 * di + bb0.y;
        float o2 = a2 * di + bb0.z, o3 = a3 * di + bb0.w;
        float o4 = a4 * di + bb1.x, o5 = a5 * di + bb1.y;
        float o6 = a6 * di + bb1.z, o7 = a7 * di + bb1.w;
        if (do_relu) {
            o0 = fmaxf(o0, 0.f); o1 = fmaxf(o1, 0.f);
            o2 = fmaxf(o2, 0.f); o3 = fmaxf(o3, 0.f);
            o4 = fmaxf(o4, 0.f); o5 = fmaxf(o5, 0.f);
            o6 = fmaxf(o6, 0.f); o7 = fmaxf(o7, 0.f);
        }
        out[(size_t)node * 16 + q] =
            make_uint4(f2h_pair(o0, o1), f2h_pair(o2, o3), f2h_pair(o4, o5), f2h_pair(o6, o7));
    }
}

// ---------------- CSR aggregation, dim 5 (fp16 packed rows): thread per node ----------------
__global__ void agg5_v2(const uint4* __restrict__ hc, const int* __restrict__ rowptr,
                        const int* __restrict__ col, const float* __restrict__ dinv,
                        const float* __restrict__ b3, float* __restrict__ out, int N) {
    int node = blockIdx.x * 256 + threadIdx.x;
    if (node >= N) return;
    float a0 = 0.f, a1 = 0.f, a2 = 0.f, a3 = 0.f, a4 = 0.f;
    int beg = rowptr[node], end = rowptr[node + 1];
#pragma unroll 2
    for (int j = beg; j < end; ++j) {
        uint4 v = hc[col[j]];
        a0 += h2f_lo(v.x); a1 += h2f_hi(v.x);
        a2 += h2f_lo(v.y); a3 += h2f_hi(v.y);
        a4 += h2f_lo(v.z);
    }
    uint4 vs = hc[node];
    a0 += h2f_lo(vs.x); a1 += h2f_hi(vs.x);
    a2 += h2f_lo(vs.y); a3 += h2f_hi(vs.y);
    a4 += h2f_lo(vs.z);
    float di = dinv[node];
    out[node * 5 + 0] = a0 * di + b3[0];
    out[node * 5 + 1] = a1 * di + b3[1];
    out[node * 5 + 2] = a2 * di + b3[2];
    out[node * 5 + 3] = a3 * di + b3[3];
    out[node * 5 + 4] = a4 * di + b3[4];
}

static inline size_t align512(size_t x) { return (x + 511) & ~(size_t)511; }

extern "C" void kernel_launch(void* const* d_in, const int* in_sizes, int n_in,
                              void* d_out, int out_size, void* d_ws, size_t ws_size,
                              hipStream_t stream) {
    const float* x  = (const float*)d_in[0];
    const int* ei   = (const int*)d_in[1];
    const float* W1 = (const float*)d_in[2];
    const float* b1 = (const float*)d_in[3];
    const float* W2 = (const float*)d_in[4];
    const float* b2 = (const float*)d_in[5];
    const float* W3 = (const float*)d_in[6];
    const float* b3 = (const float*)d_in[7];
    const int* src = ei;
    const int* dst = ei + NE;

    char* ws = (char*)d_ws;
    size_t off = 0;
    int* rowptr = (int*)(ws + off);     off += align512((size_t)(NN + 1) * 4);
    float* dinv = (float*)(ws + off);   off += align512((size_t)NN * 4);
    int* bsum = (int*)(ws + off);       off += align512((size_t)128 * 4);
    int* ghist = (int*)(ws + off);      off += align512((size_t)GH * 4);
    ushort* wt1h = (ushort*)(ws + off); off += align512((size_t)128 * 384 * 2);
    ushort* wt1l = (ushort*)(ws + off); off += align512((size_t)128 * 384 * 2);
    ushort* wt2h = (ushort*)(ws + off); off += align512((size_t)128 * 128 * 2);
    ushort* wt2l = (ushort*)(ws + off); off += align512((size_t)128 * 128 * 2);
    int* col = (int*)(ws + off);        off += align512((size_t)NE * 4);
    uint* hb = (uint*)(ws + off);       off += align512((size_t)NN * 64 * 4);   // fp16 dinv*h (packed)
    char* bufF = (char*)(ws + off);     off += align512((size_t)NN * 128 * 4);  // fp16 agg out (oversized: OOB-tile reads stay in ws)
    uint4* hc = (uint4*)(ws + off);     off += align512((size_t)NN * 16);       // packed fp16 dinv*h5
    uint* binned = (uint*)bufF;  // alias: binned dead before bufF's first write
    (void)ws_size;

    // ---- W transpose + fp16 hi/lo split ----
    wsplit<384><<<12, 256, 0, stream>>>(W1, wt1h, wt1l);
    wsplit<128><<<4, 256, 0, stream>>>(W2, wt2h, wt2l);

    // ---- build CSR (by dst) + dinv, bucket-sorted for write locality ----
    hist_bkt<<<BIN_BLOCKS, 256, 0, stream>>>(dst, ghist);
    {
        int nb = (GH + SCAN_CHUNK - 1) / SCAN_CHUNK;  // 98
        scan_p1<<<nb, 256, 0, stream>>>(ghist, bsum, GH);
        scan_p2<<<1, 128, 0, stream>>>(bsum, nb);
        scan_p3_plain<<<nb, 256, 0, stream>>>(ghist, bsum, GH);
    }
    bin_edges<<<BIN_BLOCKS, 256, 0, stream>>>(src, dst, ghist, binned);
    bucket_csr<<<NBKT, 256, 0, stream>>>(binned, ghist, rowptr, dinv, col);

    int gemm_blocks = (NN + 127) / 128;  // 782
    // ---- layer 1 ----
    mfma_gemm_f32<384><<<gemm_blocks, 256, 0, stream>>>(x, wt1h, wt1l, dinv, hb, NN);
    agg128_v3<<<(NN + 3) / 4, 256, 0, stream>>>((const uint4*)hb, rowptr, col, dinv, b1,
                                                (uint4*)bufF, NN, 1);
    // ---- layer 2 ----
    mfma_gemm_f16<<<gemm_blocks, 256, 0, stream>>>((const ushort*)bufF, wt2h, wt2l, dinv, hb, NN);
    agg128_v3<<<(NN + 3) / 4, 256, 0, stream>>>((const uint4*)hb, rowptr, col, dinv, b2,
                                                (uint4*)bufF, NN, 1);
    // ---- layer 3 ----
    gemm_n5h<<<(NN + 255) / 256, 256, 0, stream>>>((const uint4*)bufF, W3, dinv, hc, NN);
    agg5_v2<<<(NN + 255) / 256, 256, 0, stream>>>(hc, rowptr, col, dinv, b3, (float*)d_out, NN);
}